// Round 13
// baseline (302.071 us; speedup 1.0000x reference)
//
#include <hip/hip_runtime.h>

#define N_NODES 50000
#define DIM     128
#define N_EDGES 800000
#define N_LABEL 200000
#define SENT    N_NODES      // sentinel (zero) row index, fits in ushort

// column-blocked bf16 h tables: 2 parts, part p holds cols [64p, 64p+64).
// per part: (N_NODES+1) rows x 128B
#define PPU ((N_NODES + 1) * 32)   // uints per part
#define PP4 ((N_NODES + 1) * 8)    // uint4 per part

// fp8 shadow tables (aggregation gather only): full 128-col row = 128B = 1 line
#define HF8U ((N_NODES + 1) * 32)  // uints per fp8 table

// bucket partition: bucket = dst >> 5 (32 nodes/bucket), fixed capacity slots
#define NBUCK 1563           // ceil(50000/32)
#define CAP   1024           // slots per bucket (mean fill ~512, 22-sigma margin)
#define NPBLK 250            // partition blocks (graph edges)
#define CHUNK 3200           // edges per partition block

typedef __attribute__((ext_vector_type(8)))  short short8;    // 8 bf16 (4 VGPRs)
typedef __attribute__((ext_vector_type(16))) float floatx16;  // 32x32 MFMA acc

// split fp32 into bf16 hi + bf16 lo (x ~= hi + lo, rel err ~2^-17), RNE both
__device__ inline void f32_to_bf16x2(float x, unsigned short& hi, unsigned short& lo) {
    unsigned u  = __float_as_uint(x);
    unsigned rh = (u + 0x7FFFu + ((u >> 16) & 1u)) >> 16;
    hi = (unsigned short)rh;
    float hif = __uint_as_float(rh << 16);
    float r = x - hif;
    unsigned ul = __float_as_uint(r);
    unsigned rl = (ul + 0x7FFFu + ((ul >> 16) & 1u)) >> 16;
    lo = (unsigned short)rl;
}

__device__ inline unsigned short f32_to_bf16(float x) {
    unsigned u = __float_as_uint(x);
    return (unsigned short)((u + 0x7FFFu + ((u >> 16) & 1u)) >> 16);
}

__device__ inline unsigned pack_bf16x2(float a, float b) {
    return (unsigned)f32_to_bf16(a) | ((unsigned)f32_to_bf16(b) << 16);
}

__device__ inline float bf_lo(unsigned u) { return __uint_as_float(u << 16); }
__device__ inline float bf_hi(unsigned u) { return __uint_as_float(u & 0xFFFF0000u); }

// fp8 e4m3fn encode via bit trick: scale x by 2^-120 so fp8's [e:m] aligns with
// f32 bits [26:20]; RNE at bit 20. No intrinsics, exact for denormals.
__device__ inline unsigned f32_to_fp8(float x) {
    unsigned u = __float_as_uint(x * 7.52316384526264e-37f);   // x * 2^-120
    unsigned r = (u + 0x7FFFFu + ((u >> 20) & 1u)) >> 20;
    return (r & 0x7Fu) | ((u >> 24) & 0x80u);
}

// decode: returns value * 2^-120 (scale folded into the mean divisor)
__device__ inline float fp8f(unsigned b) {
    return __uint_as_float(((b & 0x80u) << 24) | ((b & 0x7Fu) << 20));
}

__device__ inline float dot8(uint4 a, uint4 b) {
    return bf_lo(a.x) * bf_lo(b.x) + bf_hi(a.x) * bf_hi(b.x)
         + bf_lo(a.y) * bf_lo(b.y) + bf_hi(a.y) * bf_hi(b.y)
         + bf_lo(a.z) * bf_lo(b.z) + bf_hi(a.z) * bf_hi(b.z)
         + bf_lo(a.w) * bf_lo(b.w) + bf_hi(a.w) * bf_hi(b.w);
}

#define DECW(A, w, j) { A[j] += fp8f((w) & 0xFFu); A[(j)+1] += fp8f(((w) >> 8) & 0xFFu); \
                        A[(j)+2] += fp8f(((w) >> 16) & 0xFFu); A[(j)+3] += fp8f((w) >> 24); }
#define DEC16(A, v) { DECW(A, (v).x, 0) DECW(A, (v).y, 4) DECW(A, (v).z, 8) DECW(A, (v).w, 12) }

// MERGED front-end (bcount pre-zeroed by hipMemsetAsync):
//  [0, NPBLK): graph-edge part_scatter chunks (LDS hist + range-reserve: ~1
//    global atomic per (block,bucket). NEVER direct-atomic: R11 measured 122us
//    from 512-deep same-address atomic serialization.)
//  [NPBLK, NPBLK+6250): build hb0 (2-part bf16) + hf0 (fp8 row table)
//  [.., +6282): swizzle W
//  last: zero sentinel rows of hb0/hb1/hf0/hf1
__global__ __launch_bounds__(256)
void build_all(const int* __restrict__ n_id,
               const float* __restrict__ emb,
               const float* __restrict__ xs,
               unsigned* __restrict__ hb0, unsigned* __restrict__ hb1,
               unsigned* __restrict__ hf0, unsigned* __restrict__ hf1,
               const int* __restrict__ src, const int* __restrict__ dst,
               int* __restrict__ bcount, unsigned* __restrict__ part,
               const float* __restrict__ W1l, const float* __restrict__ W1r,
               const float* __restrict__ W2l, const float* __restrict__ W2r,
               unsigned short* __restrict__ WfH, unsigned short* __restrict__ WfL) {
    if (blockIdx.x < NPBLK) {
        __shared__ int hist[NBUCK];      // pass1: counts; pass2: write cursors
        int t = threadIdx.x;
        for (int i = t; i < NBUCK; i += 256) hist[i] = 0;
        __syncthreads();
        int base = blockIdx.x * CHUNK;
        for (int e = base + t; e < base + CHUNK; e += 256)
            atomicAdd(&hist[dst[e] >> 5], 1);
        __syncthreads();
        for (int i = t; i < NBUCK; i += 256) {
            int c = hist[i];
            hist[i] = c ? atomicAdd(&bcount[i], c) : 0;   // reserve [base, base+c)
        }
        __syncthreads();
        for (int e = base + t; e < base + CHUNK; e += 256) {
            int d = dst[e];
            int bk = d >> 5;
            int pos = atomicAdd(&hist[bk], 1);
            part[bk * CAP + pos] = (unsigned)src[e] | ((unsigned)(d & 31) << 16);
        }
    } else if (blockIdx.x < NPBLK + 6250) {
        int t = (blockIdx.x - NPBLK) * 256 + threadIdx.x;   // < N_NODES*32 exactly
        int i = t >> 5, c = t & 31;                 // c covers cols 4c..4c+3
        float4 v;
        if (c < 16) {
            int nid = n_id[i];
            v = ((const float4*)emb)[nid * 16 + c];
        } else {
            v = ((const float4*)xs)[i * 16 + (c - 16)];
        }
        uint2 p;
        p.x = pack_bf16x2(v.x, v.y);
        p.y = pack_bf16x2(v.z, v.w);
        int pt = c >> 4;                            // part 0..1 (16 uint2 per part-row)
        ((uint2*)hb0)[(size_t)pt * (PPU / 2) + (size_t)i * 16 + (c & 15)] = p;
        // fp8 shadow row (cols 4c..4c+3 -> one uint)
        unsigned f8 = f32_to_fp8(v.x) | (f32_to_fp8(v.y) << 8)
                    | (f32_to_fp8(v.z) << 16) | (f32_to_fp8(v.w) << 24);
        hf0[(size_t)i * 32 + c] = f8;
    } else if (blockIdx.x < NPBLK + 6282) {
        int t = (blockIdx.x - NPBLK - 6250) * 256 + threadIdx.x;   // 8192 chunks
        if (t >= 8192) return;
        int L  = t & 63;
        int nt = (t >> 6) & 3;
        int ks = (t >> 8) & 7;
        int p  = (t >> 11) & 1;
        int ly = t >> 12;
        const float* Ws[4] = {W1l, W1r, W2l, W2r};
        const float* W = Ws[ly * 2 + p];
        int n = nt * 32 + (L & 31);
        int kbase = ks * 16 + (L >> 5) * 8;
        short8 hv, lv;
#pragma unroll
        for (int j = 0; j < 8; ++j) {
            unsigned short hh, ll;
            f32_to_bf16x2(W[(kbase + j) * DIM + n], hh, ll);
            hv[j] = (short)hh;
            lv[j] = (short)ll;
        }
        *(short8*)(WfH + (size_t)t * 8) = hv;
        *(short8*)(WfL + (size_t)t * 8) = lv;
    } else {
        // zero sentinel rows (row SENT) of hb0/hb1 (both parts) and hf0/hf1
        int u = threadIdx.x;
        if (u < 64) {
            int p = u >> 5;
            hb0[(size_t)p * PPU + (size_t)SENT * 32 + (u & 31)] = 0;
        } else if (u < 128) {
            int v = u - 64;
            int p = v >> 5;
            hb1[(size_t)p * PPU + (size_t)SENT * 32 + (v & 31)] = 0;
        } else if (u < 160) {
            hf0[(size_t)SENT * 32 + (u - 128)] = 0;
        } else if (u < 192) {
            hf1[(size_t)SENT * 32 + (u - 160)] = 0;
        }
    }
}

// FUSED csr-build + aggregate + linear, one 32-node tile (== csr bucket).
// CSRB=1 (layer 1): prologue builds localized csr in LDS from part[] and persists
//   lcsr + relative nbeg/nend for layer 2. CSRB=0 (layer 2): stages persisted csr.
// Gather (fp8, 128B full-row granule): 8-lane group per node; lane c8 reads uint4
//   slot c8 of the row (one line per load instruction); 4 rows in flight; 16-col
//   accumulator per lane; 2^120 decode scale folded into the mean divisor.
// Phase B: 4 waves, wave w owns cols [32w, 32w+32); A-agg from LDS bf16 tile,
//   A-self from bf16 2-part table (full precision direct path).
// FP8OUT=1: also emit fp8 output table via 4KB LDS repack (for next layer's gather).
template <int RELU, int CSRB, int FP8OUT>
__global__ __launch_bounds__(256, 6)
void fused_sage(const unsigned* __restrict__ part, const int* __restrict__ bcount,
                int* __restrict__ nbeg, int* __restrict__ nend,
                unsigned short* __restrict__ csr,
                const unsigned* __restrict__ hf,      // fp8 gather table
                const unsigned* __restrict__ hsrc,    // bf16 2-part (self term)
                const unsigned short* __restrict__ WfH,
                const unsigned short* __restrict__ WfL,
                const float* __restrict__ b,
                unsigned short* __restrict__ outb,    // bf16 2-part out
                unsigned* __restrict__ hfout) {       // fp8 out (FP8OUT)
    __shared__ uint4 aggtile[32][16];        // 8KB bf16 agg tile, swizzled slots
    __shared__ unsigned short lcsr[CAP];     // 2KB staged/built csr bucket
    __shared__ int lbe[32][2];               // per-node [beg,end) relative
    __shared__ int ldeg[32];
    __shared__ int lcur[32];
    __shared__ unsigned char f8t[32][128];   // 4KB fp8 repack tile
    int tid  = threadIdx.x;
    int lane = tid & 63;
    int bk   = blockIdx.x;
    int base = bk * CAP;
    int cnt  = bcount[bk];

    if (CSRB) {
        // ---- bucket_csr fused in: hist -> scan -> scatter (LDS-local) ----
        if (tid < 32) ldeg[tid] = 0;
        __syncthreads();
        for (int e = tid; e < cnt; e += 256)
            atomicAdd(&ldeg[part[base + e] >> 16], 1);
        __syncthreads();
        if (tid < 32) {                   // 32-wide scan in wave 0
            int v = ldeg[tid];
            int s = v;
#pragma unroll
            for (int off = 1; off < 32; off <<= 1) {
                int u = __shfl_up(s, off, 32);
                if (tid >= off) s += u;
            }
            int excl = s - v;
            lbe[tid][0] = excl;
            lbe[tid][1] = excl + v;
            lcur[tid]   = excl;
            int node = bk * 32 + tid;
            if (node < N_NODES) { nbeg[node] = excl; nend[node] = excl + v; }
        }
        __syncthreads();
        for (int e = tid; e < cnt; e += 256) {
            unsigned p = part[base + e];
            int pos = atomicAdd(&lcur[p >> 16], 1);
            lcsr[pos] = (unsigned short)(p & 0xFFFFu);
        }
        __syncthreads();
        // persist localized csr for layer 2 (fire-and-forget stores)
        for (int e = tid; e < cnt; e += 256) csr[base + e] = lcsr[e];
    } else {
        for (int e = tid; e < cnt; e += 256) lcsr[e] = csr[base + e];
        if (tid < 32) {
            int node = bk * 32 + tid;
            int b0 = 0, e0 = 0;
            if (node < N_NODES) { b0 = nbeg[node]; e0 = nend[node]; }
            lbe[tid][0] = b0; lbe[tid][1] = e0;
        }
        __syncthreads();
    }

    // ---- phase A: fp8 full-row gather; 8-lane group g8 owns node g8 ----
    {
        const uint4* F = (const uint4*)hf;
        int g8 = tid >> 3;                // node-local row 0..31
        int c8 = tid & 7;                 // uint4 slot of the 128B fp8 row
        int lb = lbe[g8][0], le = lbe[g8][1];
        float a[16] = {0.f,0.f,0.f,0.f,0.f,0.f,0.f,0.f,
                       0.f,0.f,0.f,0.f,0.f,0.f,0.f,0.f};
        for (int pos = lb; pos < le; pos += 4) {
            int r0 = (int)lcsr[pos];
            int r1 = (pos + 1 < le) ? (int)lcsr[pos + 1] : SENT;
            int r2 = (pos + 2 < le) ? (int)lcsr[pos + 2] : SENT;
            int r3 = (pos + 3 < le) ? (int)lcsr[pos + 3] : SENT;
            uint4 v0 = F[(size_t)r0 * 8 + c8];
            uint4 v1 = F[(size_t)r1 * 8 + c8];
            uint4 v2 = F[(size_t)r2 * 8 + c8];
            uint4 v3 = F[(size_t)r3 * 8 + c8];
            DEC16(a, v0); DEC16(a, v1); DEC16(a, v2); DEC16(a, v3);
        }
        // mean; 2^120 undoes the fp8-decode scale
        float rd = 1.32922799578492e36f / fmaxf((float)(le - lb), 1.0f);
        uint4 o0, o1;
        o0.x = pack_bf16x2(a[0] * rd,  a[1] * rd);
        o0.y = pack_bf16x2(a[2] * rd,  a[3] * rd);
        o0.z = pack_bf16x2(a[4] * rd,  a[5] * rd);
        o0.w = pack_bf16x2(a[6] * rd,  a[7] * rd);
        o1.x = pack_bf16x2(a[8] * rd,  a[9] * rd);
        o1.y = pack_bf16x2(a[10] * rd, a[11] * rd);
        o1.z = pack_bf16x2(a[12] * rd, a[13] * rd);
        o1.w = pack_bf16x2(a[14] * rd, a[15] * rd);
        // lane c8 holds cols 16*c8..16*c8+15 -> slots 2c8, 2c8+1 (swizzled)
        aggtile[g8][(2 * c8) ^ (g8 & 7)]     = o0;
        aggtile[g8][(2 * c8 + 1) ^ (g8 & 7)] = o1;
    }
    __syncthreads();

    // ---- phase B: MFMA, wave w owns cols [w*32, w*32+32) ----
    const uint4* H4 = (const uint4*)hsrc;
    int w    = tid >> 6;                  // col-tile index 0..3
    int ml   = lane & 31;                 // local row 0..31
    int mc   = min(bk * 32 + ml, N_NODES - 1);
    int kh   = lane >> 5;

    floatx16 acc;
#pragma unroll
    for (int i = 0; i < 16; ++i) acc[i] = 0.f;

    // agg term (A from LDS, slot kh+2*ks swizzled by row)
#pragma unroll
    for (int ks = 0; ks < 8; ++ks) {
        int slot = (kh + 2 * ks) ^ (ml & 7);
        short8 aa = *(const short8*)&aggtile[ml][slot];
        int cbase = (ks * 4 + w) * 64 + lane;
        short8 bh = *(const short8*)(WfH + (size_t)cbase * 8);
        short8 bl = *(const short8*)(WfL + (size_t)cbase * 8);
        acc = __builtin_amdgcn_mfma_f32_32x32x16_bf16(aa, bh, acc, 0, 0, 0);
        acc = __builtin_amdgcn_mfma_f32_32x32x16_bf16(aa, bl, acc, 0, 0, 0);
    }
    // self term (A from 2-part-blocked bf16 h rows)
#pragma unroll
    for (int ks = 0; ks < 8; ++ks) {
        int c8 = ks * 2 + kh;             // uint4 col-slot 0..15
        short8 aa = *(const short8*)&H4[(size_t)(c8 >> 3) * PP4 + (size_t)mc * 8 + (c8 & 7)];
        int cbase = ((8 + ks) * 4 + w) * 64 + lane;
        short8 bh = *(const short8*)(WfH + (size_t)cbase * 8);
        short8 bl = *(const short8*)(WfL + (size_t)cbase * 8);
        acc = __builtin_amdgcn_mfma_f32_32x32x16_bf16(aa, bh, acc, 0, 0, 0);
        acc = __builtin_amdgcn_mfma_f32_32x32x16_bf16(aa, bl, acc, 0, 0, 0);
    }

    int col0 = w * 32 + (lane & 31);
    float bb = b[col0];
    unsigned short* outp = outb + (size_t)(w >> 1) * (PPU * 2);   // part, ushort units
#pragma unroll
    for (int reg = 0; reg < 16; ++reg) {
        int rloc = (reg & 3) + 8 * (reg >> 2) + 4 * kh;   // C/D row map (m74/m101)
        int rowg = bk * 32 + rloc;
        if (rowg < N_NODES) {
            float v0 = acc[reg] + bb;
            if (RELU) v0 = fmaxf(v0, 0.f);
            outp[(size_t)rowg * 64 + (col0 & 63)] = f32_to_bf16(v0);
            if (FP8OUT) f8t[rloc][col0] = (unsigned char)f32_to_fp8(v0);
        }
    }
    if (FP8OUT) {
        __syncthreads();
        int r = tid >> 3, s = tid & 7;    // row 0..31, uint4 slot 0..7
        int rowg = bk * 32 + r;
        if (rowg < N_NODES)
            ((uint4*)hfout)[(size_t)rowg * 8 + s] = *(const uint4*)&f8t[r][s * 16];
    }
}

// logits from 2-part-blocked bf16 h2; 8 lanes/edge, TWO edges per lane.
// FULL-LINE loads: lane c reads uint4 slot c of part0 / part1.
__global__ void edge_dot(const int* __restrict__ esrc, const int* __restrict__ edst,
                         const unsigned* __restrict__ h2b, float* __restrict__ out) {
    int t = blockIdx.x * blockDim.x + threadIdx.x;
    int e0 = t >> 3, c = t & 7;
    const int HALF = N_LABEL / 2;
    if (e0 >= HALF) return;
    int e1 = e0 + HALF;
    const uint4* H = (const uint4*)h2b;
    int rs0 = esrc[e0], rd0 = edst[e0];
    int rs1 = esrc[e1], rd1 = edst[e1];
    uint4 a0 = H[(size_t)rs0 * 8 + c];            // src e0, part 0 (full line)
    uint4 a1 = H[PP4 + (size_t)rs0 * 8 + c];      // src e0, part 1
    uint4 b0 = H[(size_t)rd0 * 8 + c];            // dst e0, part 0
    uint4 b1 = H[PP4 + (size_t)rd0 * 8 + c];      // dst e0, part 1
    uint4 a2 = H[(size_t)rs1 * 8 + c];            // src e1, part 0
    uint4 a3 = H[PP4 + (size_t)rs1 * 8 + c];      // src e1, part 1
    uint4 b2 = H[(size_t)rd1 * 8 + c];            // dst e1, part 0
    uint4 b3 = H[PP4 + (size_t)rd1 * 8 + c];      // dst e1, part 1
    float p0 = dot8(a0, b0) + dot8(a1, b1);
    float p1 = dot8(a2, b2) + dot8(a3, b3);
#pragma unroll
    for (int off = 4; off; off >>= 1) {
        p0 += __shfl_down(p0, off, 8);
        p1 += __shfl_down(p1, off, 8);
    }
    if (c == 0) { out[e0] = p0; out[e1] = p1; }
}

extern "C" void kernel_launch(void* const* d_in, const int* in_sizes, int n_in,
                              void* d_out, int out_size, void* d_ws, size_t ws_size,
                              hipStream_t stream) {
    const int*   n_id     = (const int*)d_in[0];
    const float* x_struct = (const float*)d_in[1];
    const int*   e_idx    = (const int*)d_in[2];   // [2, N_EDGES]
    const int*   eli      = (const int*)d_in[3];   // [2, N_LABEL]
    const float* emb      = (const float*)d_in[4];
    const float* W1l      = (const float*)d_in[5];
    const float* W1r      = (const float*)d_in[6];
    const float* b1       = (const float*)d_in[7];
    const float* W2l      = (const float*)d_in[8];
    const float* W2r      = (const float*)d_in[9];
    const float* b2       = (const float*)d_in[10];
    float* out = (float*)d_out;

    const int* src = e_idx;
    const int* dst = e_idx + N_EDGES;

    const size_t ROWS = (size_t)2 * PPU;           // uints per bf16 table (2 parts)
    unsigned* hb2 = (unsigned*)d_ws;               // bf16 h2 (edge_dot input)
    unsigned* hb0 = hb2 + ROWS;                    // bf16 h0 (+sentinel)
    unsigned* hb1 = hb0 + ROWS;                    // bf16 h1 (+sentinel)
    unsigned* hf0 = hb1 + ROWS;                    // fp8 h0 (gather table)
    unsigned* hf1 = hf0 + (size_t)HF8U;            // fp8 h1 (gather table)
    int*   nbeg   = (int*)(hf1 + (size_t)HF8U);    // relative [beg,end) per node
    int*   nend   = nbeg + N_NODES;
    int*   bcount = nend + N_NODES;                // NBUCK
    unsigned* part= (unsigned*)(bcount + NBUCK);   // NBUCK*CAP packed (src|local<<16)
    unsigned short* csr = (unsigned short*)(part + (size_t)NBUCK * CAP);  // NBUCK*CAP
    uintptr_t wa  = ((uintptr_t)(csr + (size_t)NBUCK * CAP) + 15) & ~(uintptr_t)15;
    unsigned short* WfH = (unsigned short*)wa;     // 2*32768
    unsigned short* WfL = WfH + 2 * 32768;

    // bcount <- 0 (capture-safe async memset; 6KB)
    hipMemsetAsync(bcount, 0, NBUCK * sizeof(int), stream);

    // merged front-end: LDS-hist scatter + hb0/hf0 build + W swizzle + sentinels
    build_all<<<NPBLK + 6283, 256, 0, stream>>>(
        n_id, emb, x_struct, hb0, hb1, hf0, hf1, src, dst, bcount, part,
        W1l, W1r, W2l, W2r, WfH, WfL);

    // layer 1: fused csr-build + fp8-gather aggregate + linear
    //          -> bf16 h1 + fp8 h1 (persists csr)
    fused_sage<1, 1, 1><<<NBUCK, 256, 0, stream>>>(
        part, bcount, nbeg, nend, csr, hf0, hb0, WfH, WfL, b1,
        (unsigned short*)hb1, hf1);

    // layer 2: fused fp8-gather aggregate + linear -> bf16 h2
    fused_sage<0, 0, 0><<<NBUCK, 256, 0, stream>>>(
        part, bcount, nbeg, nend, csr, hf1, hb1, WfH + 32768, WfL + 32768, b2,
        (unsigned short*)hb2, nullptr);

    edge_dot<<<(N_LABEL / 2 * 8 + 255) / 256, 256, 0, stream>>>(
        eli, eli + N_LABEL, hb2, out);
}

// Round 14
// 215.708 us; speedup vs baseline: 1.4004x; 1.4004x over previous
//
#include <hip/hip_runtime.h>

#define N_NODES 50000
#define DIM     128
#define N_EDGES 800000
#define N_LABEL 200000
#define SENT    N_NODES      // sentinel (zero) row index, fits in ushort

// column-blocked bf16 h tables: 2 parts, part p holds cols [64p, 64p+64).
// per part: (N_NODES+1) rows x 128B
#define PPU ((N_NODES + 1) * 32)   // uints per part
#define PP4 ((N_NODES + 1) * 8)    // uint4 per part

// fp8 shadow tables (aggregation gather only): full 128-col row = 128B = 1 line
#define HF8U ((N_NODES + 1) * 32)  // uints per fp8 table

// bucket partition: bucket = dst >> 5 (32 nodes/bucket), fixed capacity slots
#define NBUCK 1563           // ceil(50000/32)
#define CAP   1024           // slots per bucket (mean fill ~512, 22-sigma margin)
#define NPBLK 250            // partition blocks (graph edges)
#define CHUNK 3200           // edges per partition block

typedef __attribute__((ext_vector_type(8)))  short short8;    // 8 bf16 (4 VGPRs)
typedef __attribute__((ext_vector_type(16))) float floatx16;  // 32x32 MFMA acc

// split fp32 into bf16 hi + bf16 lo (x ~= hi + lo, rel err ~2^-17), RNE both
__device__ inline void f32_to_bf16x2(float x, unsigned short& hi, unsigned short& lo) {
    unsigned u  = __float_as_uint(x);
    unsigned rh = (u + 0x7FFFu + ((u >> 16) & 1u)) >> 16;
    hi = (unsigned short)rh;
    float hif = __uint_as_float(rh << 16);
    float r = x - hif;
    unsigned ul = __float_as_uint(r);
    unsigned rl = (ul + 0x7FFFu + ((ul >> 16) & 1u)) >> 16;
    lo = (unsigned short)rl;
}

__device__ inline unsigned short f32_to_bf16(float x) {
    unsigned u = __float_as_uint(x);
    return (unsigned short)((u + 0x7FFFu + ((u >> 16) & 1u)) >> 16);
}

__device__ inline unsigned pack_bf16x2(float a, float b) {
    return (unsigned)f32_to_bf16(a) | ((unsigned)f32_to_bf16(b) << 16);
}

__device__ inline float bf_lo(unsigned u) { return __uint_as_float(u << 16); }
__device__ inline float bf_hi(unsigned u) { return __uint_as_float(u & 0xFFFF0000u); }

// fp8 e4m3fn encode via bit trick: scale x by 2^-120 so fp8's [e:m] aligns with
// f32 bits [26:20]; RNE at bit 20. No intrinsics.
__device__ inline unsigned f32_to_fp8(float x) {
    unsigned u = __float_as_uint(x * 7.52316384526264e-37f);   // x * 2^-120
    unsigned r = (u + 0x7FFFFu + ((u >> 20) & 1u)) >> 20;
    return (r & 0x7Fu) | ((u >> 24) & 0x80u);
}

// decode: returns value * 2^-120 (scale folded into the mean divisor)
__device__ inline float fp8f(unsigned b) {
    return __uint_as_float(((b & 0x80u) << 24) | ((b & 0x7Fu) << 20));
}

__device__ inline float dot8(uint4 a, uint4 b) {
    return bf_lo(a.x) * bf_lo(b.x) + bf_hi(a.x) * bf_hi(b.x)
         + bf_lo(a.y) * bf_lo(b.y) + bf_hi(a.y) * bf_hi(b.y)
         + bf_lo(a.z) * bf_lo(b.z) + bf_hi(a.z) * bf_hi(b.z)
         + bf_lo(a.w) * bf_lo(b.w) + bf_hi(a.w) * bf_hi(b.w);
}

#define DECW(A, w, j) { A[j] += fp8f((w) & 0xFFu); A[(j)+1] += fp8f(((w) >> 8) & 0xFFu); \
                        A[(j)+2] += fp8f(((w) >> 16) & 0xFFu); A[(j)+3] += fp8f((w) >> 24); }

// MERGED front-end (bcount pre-zeroed by hipMemsetAsync):
//  [0, NPBLK): graph-edge part_scatter chunks (LDS hist + range-reserve: ~1
//    global atomic per (block,bucket). NEVER direct-atomic: R11 measured 122us
//    from 512-deep same-address atomic serialization.)
//  [NPBLK, NPBLK+6250): build hb0 (2-part bf16) + hf0 (fp8 row table)
//  [.., +6282): swizzle W
//  last: zero sentinel rows of hb0/hb1/hf0/hf1
__global__ __launch_bounds__(256)
void build_all(const int* __restrict__ n_id,
               const float* __restrict__ emb,
               const float* __restrict__ xs,
               unsigned* __restrict__ hb0, unsigned* __restrict__ hb1,
               unsigned* __restrict__ hf0, unsigned* __restrict__ hf1,
               const int* __restrict__ src, const int* __restrict__ dst,
               int* __restrict__ bcount, unsigned* __restrict__ part,
               const float* __restrict__ W1l, const float* __restrict__ W1r,
               const float* __restrict__ W2l, const float* __restrict__ W2r,
               unsigned short* __restrict__ WfH, unsigned short* __restrict__ WfL) {
    if (blockIdx.x < NPBLK) {
        __shared__ int hist[NBUCK];      // pass1: counts; pass2: write cursors
        int t = threadIdx.x;
        for (int i = t; i < NBUCK; i += 256) hist[i] = 0;
        __syncthreads();
        int base = blockIdx.x * CHUNK;
        for (int e = base + t; e < base + CHUNK; e += 256)
            atomicAdd(&hist[dst[e] >> 5], 1);
        __syncthreads();
        for (int i = t; i < NBUCK; i += 256) {
            int c = hist[i];
            hist[i] = c ? atomicAdd(&bcount[i], c) : 0;   // reserve [base, base+c)
        }
        __syncthreads();
        for (int e = base + t; e < base + CHUNK; e += 256) {
            int d = dst[e];
            int bk = d >> 5;
            int pos = atomicAdd(&hist[bk], 1);
            part[bk * CAP + pos] = (unsigned)src[e] | ((unsigned)(d & 31) << 16);
        }
    } else if (blockIdx.x < NPBLK + 6250) {
        int t = (blockIdx.x - NPBLK) * 256 + threadIdx.x;   // < N_NODES*32 exactly
        int i = t >> 5, c = t & 31;                 // c covers cols 4c..4c+3
        float4 v;
        if (c < 16) {
            int nid = n_id[i];
            v = ((const float4*)emb)[nid * 16 + c];
        } else {
            v = ((const float4*)xs)[i * 16 + (c - 16)];
        }
        uint2 p;
        p.x = pack_bf16x2(v.x, v.y);
        p.y = pack_bf16x2(v.z, v.w);
        int pt = c >> 4;                            // part 0..1 (16 uint2 per part-row)
        ((uint2*)hb0)[(size_t)pt * (PPU / 2) + (size_t)i * 16 + (c & 15)] = p;
        // fp8 shadow row (cols 4c..4c+3 -> one uint)
        unsigned f8 = f32_to_fp8(v.x) | (f32_to_fp8(v.y) << 8)
                    | (f32_to_fp8(v.z) << 16) | (f32_to_fp8(v.w) << 24);
        hf0[(size_t)i * 32 + c] = f8;
    } else if (blockIdx.x < NPBLK + 6282) {
        int t = (blockIdx.x - NPBLK - 6250) * 256 + threadIdx.x;   // 8192 chunks
        if (t >= 8192) return;
        int L  = t & 63;
        int nt = (t >> 6) & 3;
        int ks = (t >> 8) & 7;
        int p  = (t >> 11) & 1;
        int ly = t >> 12;
        const float* Ws[4] = {W1l, W1r, W2l, W2r};
        const float* W = Ws[ly * 2 + p];
        int n = nt * 32 + (L & 31);
        int kbase = ks * 16 + (L >> 5) * 8;
        short8 hv, lv;
#pragma unroll
        for (int j = 0; j < 8; ++j) {
            unsigned short hh, ll;
            f32_to_bf16x2(W[(kbase + j) * DIM + n], hh, ll);
            hv[j] = (short)hh;
            lv[j] = (short)ll;
        }
        *(short8*)(WfH + (size_t)t * 8) = hv;
        *(short8*)(WfL + (size_t)t * 8) = lv;
    } else {
        // zero sentinel rows (row SENT) of hb0/hb1 (both parts) and hf0/hf1
        int u = threadIdx.x;
        if (u < 64) {
            int p = u >> 5;
            hb0[(size_t)p * PPU + (size_t)SENT * 32 + (u & 31)] = 0;
        } else if (u < 128) {
            int v = u - 64;
            int p = v >> 5;
            hb1[(size_t)p * PPU + (size_t)SENT * 32 + (v & 31)] = 0;
        } else if (u < 160) {
            hf0[(size_t)SENT * 32 + (u - 128)] = 0;
        } else if (u < 192) {
            hf1[(size_t)SENT * 32 + (u - 160)] = 0;
        }
    }
}

// FUSED csr-build + aggregate + linear, one 32-node tile (== csr bucket).
// CSRB=1 (layer 1): prologue builds localized csr in LDS from part[] and persists
//   lcsr + relative nbeg/nend for layer 2. CSRB=0 (layer 2): stages persisted csr.
// Gather (fp8, 128B full-row granule, LOW-PRESSURE form): 16-lane group, 2 nodes
//   sequential (R12's proven VGPR-32 shape); lane c loads uint2 slot c of the row
//   (16 lanes x 8B = one line per load instruction); 4 rows in flight; a[8]/lane.
//   R13's a[16]+uint4 form spilled to scratch (WRITE_SIZE 148MB) - never again.
// Phase B: 4 waves, wave w owns cols [32w, 32w+32); A-agg from LDS bf16 tile,
//   A-self from bf16 2-part table (full precision direct path).
// FP8OUT=1: also emit fp8 output table via 4KB LDS repack (next layer's gather).
template <int RELU, int CSRB, int FP8OUT>
__global__ __launch_bounds__(256, 7)
void fused_sage(const unsigned* __restrict__ part, const int* __restrict__ bcount,
                int* __restrict__ nbeg, int* __restrict__ nend,
                unsigned short* __restrict__ csr,
                const unsigned* __restrict__ hf,      // fp8 gather table
                const unsigned* __restrict__ hsrc,    // bf16 2-part (self term)
                const unsigned short* __restrict__ WfH,
                const unsigned short* __restrict__ WfL,
                const float* __restrict__ b,
                unsigned short* __restrict__ outb,    // bf16 2-part out
                unsigned* __restrict__ hfout) {       // fp8 out (FP8OUT)
    __shared__ uint4 aggtile[32][16];        // 8KB bf16 agg tile, swizzled slots
    __shared__ unsigned short lcsr[CAP];     // 2KB staged/built csr bucket
    __shared__ int lbe[32][2];               // per-node [beg,end) relative
    __shared__ int ldeg[32];
    __shared__ int lcur[32];
    __shared__ unsigned char f8t[32][128];   // 4KB fp8 repack tile
    int tid  = threadIdx.x;
    int lane = tid & 63;
    int bk   = blockIdx.x;
    int base = bk * CAP;
    int cnt  = bcount[bk];

    if (CSRB) {
        // ---- bucket_csr fused in: hist -> scan -> scatter (LDS-local) ----
        if (tid < 32) ldeg[tid] = 0;
        __syncthreads();
        for (int e = tid; e < cnt; e += 256)
            atomicAdd(&ldeg[part[base + e] >> 16], 1);
        __syncthreads();
        if (tid < 32) {                   // 32-wide scan in wave 0
            int v = ldeg[tid];
            int s = v;
#pragma unroll
            for (int off = 1; off < 32; off <<= 1) {
                int u = __shfl_up(s, off, 32);
                if (tid >= off) s += u;
            }
            int excl = s - v;
            lbe[tid][0] = excl;
            lbe[tid][1] = excl + v;
            lcur[tid]   = excl;
            int node = bk * 32 + tid;
            if (node < N_NODES) { nbeg[node] = excl; nend[node] = excl + v; }
        }
        __syncthreads();
        for (int e = tid; e < cnt; e += 256) {
            unsigned p = part[base + e];
            int pos = atomicAdd(&lcur[p >> 16], 1);
            lcsr[pos] = (unsigned short)(p & 0xFFFFu);
        }
        __syncthreads();
        // persist localized csr for layer 2 (fire-and-forget stores)
        for (int e = tid; e < cnt; e += 256) csr[base + e] = lcsr[e];
    } else {
        for (int e = tid; e < cnt; e += 256) lcsr[e] = csr[base + e];
        if (tid < 32) {
            int node = bk * 32 + tid;
            int b0 = 0, e0 = 0;
            if (node < N_NODES) { b0 = nbeg[node]; e0 = nend[node]; }
            lbe[tid][0] = b0; lbe[tid][1] = e0;
        }
        __syncthreads();
    }

    // ---- phase A: fp8 full-row gather; 16-lane group, 2 nodes sequential ----
    {
        const uint2* F2 = (const uint2*)hf;
        int g = tid >> 4;                 // group 0..15
        int c = tid & 15;                 // uint2 slot of the 128B fp8 row
#pragma unroll
        for (int nn = 0; nn < 2; ++nn) {
            int nl = g + nn * 16;
            int lb = lbe[nl][0], le = lbe[nl][1];
            float a[8] = {0.f,0.f,0.f,0.f,0.f,0.f,0.f,0.f};
            for (int pos = lb; pos < le; pos += 4) {
                int r0 = (int)lcsr[pos];
                int r1 = (pos + 1 < le) ? (int)lcsr[pos + 1] : SENT;
                int r2 = (pos + 2 < le) ? (int)lcsr[pos + 2] : SENT;
                int r3 = (pos + 3 < le) ? (int)lcsr[pos + 3] : SENT;
                uint2 v0 = F2[(size_t)r0 * 16 + c];
                uint2 v1 = F2[(size_t)r1 * 16 + c];
                uint2 v2 = F2[(size_t)r2 * 16 + c];
                uint2 v3 = F2[(size_t)r3 * 16 + c];
                DECW(a, v0.x, 0) DECW(a, v0.y, 4)
                DECW(a, v1.x, 0) DECW(a, v1.y, 4)
                DECW(a, v2.x, 0) DECW(a, v2.y, 4)
                DECW(a, v3.x, 0) DECW(a, v3.y, 4)
            }
            // mean; 2^120 undoes the fp8-decode scale
            float rd = 1.32922799578492e36f / fmaxf((float)(le - lb), 1.0f);
            uint4 o;
            o.x = pack_bf16x2(a[0] * rd, a[1] * rd);
            o.y = pack_bf16x2(a[2] * rd, a[3] * rd);
            o.z = pack_bf16x2(a[4] * rd, a[5] * rd);
            o.w = pack_bf16x2(a[6] * rd, a[7] * rd);
            aggtile[nl][c ^ (nl & 7)] = o;    // slot c <-> cols 8c..8c+7
        }
    }
    __syncthreads();

    // ---- phase B: MFMA, wave w owns cols [w*32, w*32+32) ----
    const uint4* H4 = (const uint4*)hsrc;
    int w    = tid >> 6;                  // col-tile index 0..3
    int ml   = lane & 31;                 // local row 0..31
    int mc   = min(bk * 32 + ml, N_NODES - 1);
    int kh   = lane >> 5;

    floatx16 acc;
#pragma unroll
    for (int i = 0; i < 16; ++i) acc[i] = 0.f;

    // agg term (A from LDS, slot kh+2*ks swizzled by row)
#pragma unroll
    for (int ks = 0; ks < 8; ++ks) {
        int slot = (kh + 2 * ks) ^ (ml & 7);
        short8 aa = *(const short8*)&aggtile[ml][slot];
        int cbase = (ks * 4 + w) * 64 + lane;
        short8 bh = *(const short8*)(WfH + (size_t)cbase * 8);
        short8 bl = *(const short8*)(WfL + (size_t)cbase * 8);
        acc = __builtin_amdgcn_mfma_f32_32x32x16_bf16(aa, bh, acc, 0, 0, 0);
        acc = __builtin_amdgcn_mfma_f32_32x32x16_bf16(aa, bl, acc, 0, 0, 0);
    }
    // self term (A from 2-part-blocked bf16 h rows)
#pragma unroll
    for (int ks = 0; ks < 8; ++ks) {
        int c8 = ks * 2 + kh;             // uint4 col-slot 0..15
        short8 aa = *(const short8*)&H4[(size_t)(c8 >> 3) * PP4 + (size_t)mc * 8 + (c8 & 7)];
        int cbase = ((8 + ks) * 4 + w) * 64 + lane;
        short8 bh = *(const short8*)(WfH + (size_t)cbase * 8);
        short8 bl = *(const short8*)(WfL + (size_t)cbase * 8);
        acc = __builtin_amdgcn_mfma_f32_32x32x16_bf16(aa, bh, acc, 0, 0, 0);
        acc = __builtin_amdgcn_mfma_f32_32x32x16_bf16(aa, bl, acc, 0, 0, 0);
    }

    int col0 = w * 32 + (lane & 31);
    float bb = b[col0];
    unsigned short* outp = outb + (size_t)(w >> 1) * (PPU * 2);   // part, ushort units
#pragma unroll
    for (int reg = 0; reg < 16; ++reg) {
        int rloc = (reg & 3) + 8 * (reg >> 2) + 4 * kh;   // C/D row map (m74/m101)
        int rowg = bk * 32 + rloc;
        if (rowg < N_NODES) {
            float v0 = acc[reg] + bb;
            if (RELU) v0 = fmaxf(v0, 0.f);
            outp[(size_t)rowg * 64 + (col0 & 63)] = f32_to_bf16(v0);
            if (FP8OUT) f8t[rloc][col0] = (unsigned char)f32_to_fp8(v0);
        }
    }
    if (FP8OUT) {
        __syncthreads();
        int r = tid >> 3, s = tid & 7;    // row 0..31, uint4 slot 0..7
        int rowg = bk * 32 + r;
        if (rowg < N_NODES)
            ((uint4*)hfout)[(size_t)rowg * 8 + s] = *(const uint4*)&f8t[r][s * 16];
    }
}

// logits from 2-part-blocked bf16 h2; 8 lanes/edge, TWO edges per lane.
// FULL-LINE loads: lane c reads uint4 slot c of part0 / part1.
__global__ void edge_dot(const int* __restrict__ esrc, const int* __restrict__ edst,
                         const unsigned* __restrict__ h2b, float* __restrict__ out) {
    int t = blockIdx.x * blockDim.x + threadIdx.x;
    int e0 = t >> 3, c = t & 7;
    const int HALF = N_LABEL / 2;
    if (e0 >= HALF) return;
    int e1 = e0 + HALF;
    const uint4* H = (const uint4*)h2b;
    int rs0 = esrc[e0], rd0 = edst[e0];
    int rs1 = esrc[e1], rd1 = edst[e1];
    uint4 a0 = H[(size_t)rs0 * 8 + c];            // src e0, part 0 (full line)
    uint4 a1 = H[PP4 + (size_t)rs0 * 8 + c];      // src e0, part 1
    uint4 b0 = H[(size_t)rd0 * 8 + c];            // dst e0, part 0
    uint4 b1 = H[PP4 + (size_t)rd0 * 8 + c];      // dst e0, part 1
    uint4 a2 = H[(size_t)rs1 * 8 + c];            // src e1, part 0
    uint4 a3 = H[PP4 + (size_t)rs1 * 8 + c];      // src e1, part 1
    uint4 b2 = H[(size_t)rd1 * 8 + c];            // dst e1, part 0
    uint4 b3 = H[PP4 + (size_t)rd1 * 8 + c];      // dst e1, part 1
    float p0 = dot8(a0, b0) + dot8(a1, b1);
    float p1 = dot8(a2, b2) + dot8(a3, b3);
#pragma unroll
    for (int off = 4; off; off >>= 1) {
        p0 += __shfl_down(p0, off, 8);
        p1 += __shfl_down(p1, off, 8);
    }
    if (c == 0) { out[e0] = p0; out[e1] = p1; }
}

extern "C" void kernel_launch(void* const* d_in, const int* in_sizes, int n_in,
                              void* d_out, int out_size, void* d_ws, size_t ws_size,
                              hipStream_t stream) {
    const int*   n_id     = (const int*)d_in[0];
    const float* x_struct = (const float*)d_in[1];
    const int*   e_idx    = (const int*)d_in[2];   // [2, N_EDGES]
    const int*   eli      = (const int*)d_in[3];   // [2, N_LABEL]
    const float* emb      = (const float*)d_in[4];
    const float* W1l      = (const float*)d_in[5];
    const float* W1r      = (const float*)d_in[6];
    const float* b1       = (const float*)d_in[7];
    const float* W2l      = (const float*)d_in[8];
    const float* W2r      = (const float*)d_in[9];
    const float* b2       = (const float*)d_in[10];
    float* out = (float*)d_out;

    const int* src = e_idx;
    const int* dst = e_idx + N_EDGES;

    const size_t ROWS = (size_t)2 * PPU;           // uints per bf16 table (2 parts)
    unsigned* hb2 = (unsigned*)d_ws;               // bf16 h2 (edge_dot input)
    unsigned* hb0 = hb2 + ROWS;                    // bf16 h0 (+sentinel)
    unsigned* hb1 = hb0 + ROWS;                    // bf16 h1 (+sentinel)
    unsigned* hf0 = hb1 + ROWS;                    // fp8 h0 (gather table)
    unsigned* hf1 = hf0 + (size_t)HF8U;            // fp8 h1 (gather table)
    int*   nbeg   = (int*)(hf1 + (size_t)HF8U);    // relative [beg,end) per node
    int*   nend   = nbeg + N_NODES;
    int*   bcount = nend + N_NODES;                // NBUCK
    unsigned* part= (unsigned*)(bcount + NBUCK);   // NBUCK*CAP packed (src|local<<16)
    unsigned short* csr = (unsigned short*)(part + (size_t)NBUCK * CAP);  // NBUCK*CAP
    uintptr_t wa  = ((uintptr_t)(csr + (size_t)NBUCK * CAP) + 15) & ~(uintptr_t)15;
    unsigned short* WfH = (unsigned short*)wa;     // 2*32768
    unsigned short* WfL = WfH + 2 * 32768;

    // bcount <- 0 (capture-safe async memset; 6KB)
    hipMemsetAsync(bcount, 0, NBUCK * sizeof(int), stream);

    // merged front-end: LDS-hist scatter + hb0/hf0 build + W swizzle + sentinels
    build_all<<<NPBLK + 6283, 256, 0, stream>>>(
        n_id, emb, x_struct, hb0, hb1, hf0, hf1, src, dst, bcount, part,
        W1l, W1r, W2l, W2r, WfH, WfL);

    // layer 1: fused csr-build + fp8-gather aggregate + linear
    //          -> bf16 h1 + fp8 h1 (persists csr)
    fused_sage<1, 1, 1><<<NBUCK, 256, 0, stream>>>(
        part, bcount, nbeg, nend, csr, hf0, hb0, WfH, WfL, b1,
        (unsigned short*)hb1, hf1);

    // layer 2: fused fp8-gather aggregate + linear -> bf16 h2
    fused_sage<0, 0, 0><<<NBUCK, 256, 0, stream>>>(
        part, bcount, nbeg, nend, csr, hf1, hb1, WfH + 32768, WfL + 32768, b2,
        (unsigned short*)hb2, nullptr);

    edge_dot<<<(N_LABEL / 2 * 8 + 255) / 256, 256, 0, stream>>>(
        eli, eli + N_LABEL, hb2, out);
}

// Round 15
// 215.378 us; speedup vs baseline: 1.4025x; 1.0015x over previous
//
#include <hip/hip_runtime.h>

#define N_NODES 50000
#define DIM     128
#define N_EDGES 800000
#define N_LABEL 200000
#define SENT    N_NODES      // sentinel (zero) row index, fits in ushort

// column-blocked h tables: 2 parts, part p holds cols [64p, 64p+64) of all rows.
// per part: (N_NODES+1) rows x 128B  -> gather granule = one 128B line
#define PPU ((N_NODES + 1) * 32)   // uints per part
#define PP4 ((N_NODES + 1) * 8)    // uint4 per part

// bucket partition: bucket = dst >> 5 (32 nodes/bucket), fixed capacity slots
#define NBUCK 1563           // ceil(50000/32)
#define CAP   1024           // slots per bucket (mean fill ~512, 22-sigma margin)
#define NPBLK 500            // partition blocks (graph edges) - halved serial tail
#define CHUNK 1600           // edges per partition block (500*1600 == N_EDGES)

typedef __attribute__((ext_vector_type(8)))  short short8;    // 8 bf16 (4 VGPRs)
typedef __attribute__((ext_vector_type(16))) float floatx16;  // 32x32 MFMA acc

// split fp32 into bf16 hi + bf16 lo (x ~= hi + lo, rel err ~2^-17), RNE both
__device__ inline void f32_to_bf16x2(float x, unsigned short& hi, unsigned short& lo) {
    unsigned u  = __float_as_uint(x);
    unsigned rh = (u + 0x7FFFu + ((u >> 16) & 1u)) >> 16;
    hi = (unsigned short)rh;
    float hif = __uint_as_float(rh << 16);
    float r = x - hif;
    unsigned ul = __float_as_uint(r);
    unsigned rl = (ul + 0x7FFFu + ((ul >> 16) & 1u)) >> 16;
    lo = (unsigned short)rl;
}

__device__ inline unsigned short f32_to_bf16(float x) {
    unsigned u = __float_as_uint(x);
    return (unsigned short)((u + 0x7FFFu + ((u >> 16) & 1u)) >> 16);
}

__device__ inline unsigned pack_bf16x2(float a, float b) {
    return (unsigned)f32_to_bf16(a) | ((unsigned)f32_to_bf16(b) << 16);
}

__device__ inline float bf_lo(unsigned u) { return __uint_as_float(u << 16); }
__device__ inline float bf_hi(unsigned u) { return __uint_as_float(u & 0xFFFF0000u); }

__device__ inline float dot8(uint4 a, uint4 b) {
    return bf_lo(a.x) * bf_lo(b.x) + bf_hi(a.x) * bf_hi(b.x)
         + bf_lo(a.y) * bf_lo(b.y) + bf_hi(a.y) * bf_hi(b.y)
         + bf_lo(a.z) * bf_lo(b.z) + bf_hi(a.z) * bf_hi(b.z)
         + bf_lo(a.w) * bf_lo(b.w) + bf_hi(a.w) * bf_hi(b.w);
}

// MERGED front-end (bcount pre-zeroed by hipMemsetAsync):
//  [0, NPBLK): graph-edge part_scatter chunks (LDS hist + range-reserve: ~1-2
//    global atomics per (block,bucket) -> low contention. NEVER direct-atomic:
//    R11 measured 122us from 512-deep same-address atomic serialization.)
//  [NPBLK, NPBLK+6250): build hb0 (2-part-blocked bf16)
//  [.., +6282): swizzle W
//  last: zero sentinel rows of hb0/hb1
__global__ __launch_bounds__(256)
void build_all(const int* __restrict__ n_id,
               const float* __restrict__ emb,
               const float* __restrict__ xs,
               unsigned* __restrict__ hb0, unsigned* __restrict__ hb1,
               const int* __restrict__ src, const int* __restrict__ dst,
               int* __restrict__ bcount, unsigned* __restrict__ part,
               const float* __restrict__ W1l, const float* __restrict__ W1r,
               const float* __restrict__ W2l, const float* __restrict__ W2r,
               unsigned short* __restrict__ WfH, unsigned short* __restrict__ WfL) {
    if (blockIdx.x < NPBLK) {
        // fused hist + range-reserve + grouped scatter for one graph-edge chunk
        __shared__ int hist[NBUCK];      // pass1: counts; pass2: write cursors
        int t = threadIdx.x;
        for (int i = t; i < NBUCK; i += 256) hist[i] = 0;
        __syncthreads();
        int base = blockIdx.x * CHUNK;
        for (int e = base + t; e < base + CHUNK; e += 256)
            atomicAdd(&hist[dst[e] >> 5], 1);
        __syncthreads();
        for (int i = t; i < NBUCK; i += 256) {
            int c = hist[i];
            hist[i] = c ? atomicAdd(&bcount[i], c) : 0;   // reserve [base, base+c)
        }
        __syncthreads();
        for (int e = base + t; e < base + CHUNK; e += 256) {
            int d = dst[e];
            int bk = d >> 5;
            int pos = atomicAdd(&hist[bk], 1);
            part[bk * CAP + pos] = (unsigned)src[e] | ((unsigned)(d & 31) << 16);
        }
    } else if (blockIdx.x < NPBLK + 6250) {
        int t = (blockIdx.x - NPBLK) * 256 + threadIdx.x;   // < N_NODES*32 exactly
        int i = t >> 5, c = t & 31;                 // c covers cols 4c..4c+3
        float4 v;
        if (c < 16) {
            int nid = n_id[i];
            v = ((const float4*)emb)[nid * 16 + c];
        } else {
            v = ((const float4*)xs)[i * 16 + (c - 16)];
        }
        uint2 p;
        p.x = pack_bf16x2(v.x, v.y);
        p.y = pack_bf16x2(v.z, v.w);
        int pt = c >> 4;                            // part 0..1 (16 uint2 per part-row)
        ((uint2*)hb0)[(size_t)pt * (PPU / 2) + (size_t)i * 16 + (c & 15)] = p;
    } else if (blockIdx.x < NPBLK + 6282) {
        int t = (blockIdx.x - NPBLK - 6250) * 256 + threadIdx.x;   // 8192 chunks
        if (t >= 8192) return;
        int L  = t & 63;
        int nt = (t >> 6) & 3;
        int ks = (t >> 8) & 7;
        int p  = (t >> 11) & 1;
        int ly = t >> 12;
        const float* Ws[4] = {W1l, W1r, W2l, W2r};
        const float* W = Ws[ly * 2 + p];
        int n = nt * 32 + (L & 31);
        int kbase = ks * 16 + (L >> 5) * 8;
        short8 hv, lv;
#pragma unroll
        for (int j = 0; j < 8; ++j) {
            unsigned short hh, ll;
            f32_to_bf16x2(W[(kbase + j) * DIM + n], hh, ll);
            hv[j] = (short)hh;
            lv[j] = (short)ll;
        }
        *(short8*)(WfH + (size_t)t * 8) = hv;
        *(short8*)(WfL + (size_t)t * 8) = lv;
    } else {
        // zero sentinel rows (row SENT) of both parts of hb0 and hb1
        int u = threadIdx.x;
        if (u < 64) {
            int p = u >> 5;
            hb0[(size_t)p * PPU + (size_t)SENT * 32 + (u & 31)] = 0;
        } else if (u < 128) {
            int v = u - 64;
            int p = v >> 5;
            hb1[(size_t)p * PPU + (size_t)SENT * 32 + (v & 31)] = 0;
        }
    }
}

#define ACC8(A, v) { A[0]+=bf_lo((v).x); A[1]+=bf_hi((v).x); A[2]+=bf_lo((v).y); A[3]+=bf_hi((v).y); \
                     A[4]+=bf_lo((v).z); A[5]+=bf_hi((v).z); A[6]+=bf_lo((v).w); A[7]+=bf_hi((v).w); }

// FUSED csr-build + aggregate + linear, one 32-node tile (== csr bucket).
// CSRB=1 (layer 1): prologue builds localized csr in LDS from part[] and persists
//   lcsr + relative nbeg/nend for layer 2. CSRB=0 (layer 2): stages persisted csr.
// Gather (128B granule): 2 column phases over 2-part-blocked h; per 16-lane group:
//   q=c&7 (uint4 slot of the 128B row-slice), rsl=c>>3 (2 interleaved position
//   chains); 4 rows x 128B in flight per burst; shfl_xor(8) reduce.
// Phase B: 4 waves, wave w owns cols [32w, 32w+32).
template <int RELU, int CSRB>
__global__ __launch_bounds__(256, 7)
void fused_sage(const unsigned* __restrict__ part, const int* __restrict__ bcount,
                int* __restrict__ nbeg, int* __restrict__ nend,
                unsigned short* __restrict__ csr,
                const unsigned* __restrict__ hsrc,
                const unsigned short* __restrict__ WfH,
                const unsigned short* __restrict__ WfL,
                const float* __restrict__ b,
                unsigned short* __restrict__ outb) {
    __shared__ uint4 aggtile[32][16];        // 8KB bf16 agg tile, swizzled slots
    __shared__ unsigned short lcsr[CAP];     // 2KB staged/built csr bucket
    __shared__ int lbe[32][2];               // per-node [beg,end) relative
    __shared__ int ldeg[32];
    __shared__ int lcur[32];
    int tid  = threadIdx.x;
    int lane = tid & 63;
    int g    = tid >> 4;                  // 16-lane group id (0..15)
    int c    = tid & 15;
    int bk   = blockIdx.x;
    int base = bk * CAP;
    int cnt  = bcount[bk];

    if (CSRB) {
        // ---- bucket_csr fused in: hist -> scan -> scatter (LDS-local) ----
        if (tid < 32) ldeg[tid] = 0;
        __syncthreads();
        for (int e = tid; e < cnt; e += 256)
            atomicAdd(&ldeg[part[base + e] >> 16], 1);
        __syncthreads();
        if (tid < 32) {                   // 32-wide scan in wave 0
            int v = ldeg[tid];
            int s = v;
#pragma unroll
            for (int off = 1; off < 32; off <<= 1) {
                int u = __shfl_up(s, off, 32);
                if (tid >= off) s += u;
            }
            int excl = s - v;
            lbe[tid][0] = excl;
            lbe[tid][1] = excl + v;
            lcur[tid]   = excl;
            int node = bk * 32 + tid;
            if (node < N_NODES) { nbeg[node] = excl; nend[node] = excl + v; }
        }
        __syncthreads();
        for (int e = tid; e < cnt; e += 256) {
            unsigned p = part[base + e];
            int pos = atomicAdd(&lcur[p >> 16], 1);
            lcsr[pos] = (unsigned short)(p & 0xFFFFu);
        }
        __syncthreads();
        // persist localized csr for layer 2 (fire-and-forget stores)
        for (int e = tid; e < cnt; e += 256) csr[base + e] = lcsr[e];
    } else {
        for (int e = tid; e < cnt; e += 256) lcsr[e] = csr[base + e];
        if (tid < 32) {
            int node = bk * 32 + tid;
            int b0 = 0, e0 = 0;
            if (node < N_NODES) { b0 = nbeg[node]; e0 = nend[node]; }
            lbe[tid][0] = b0; lbe[tid][1] = e0;
        }
        __syncthreads();
    }

    const uint4* H4 = (const uint4*)hsrc;
    int q   = c & 7;                      // uint4 col-slot within 128B row-slice
    int rsl = c >> 3;                     // position chain 0..1

    // ---- phase A: 2 column phases (no inter-phase sync; slots disjoint) ----
    for (int p = 0; p < 2; ++p) {
        const uint4* Hp = H4 + (size_t)p * PP4;
#pragma unroll
        for (int nn = 0; nn < 2; ++nn) {
            int nl = g + nn * 16;
            int lb = lbe[nl][0], le = lbe[nl][1];
            float a[8] = {0.f,0.f,0.f,0.f,0.f,0.f,0.f,0.f};
            for (int pos = lb + rsl; pos < le; pos += 8) {
                int p1 = pos + 2, p2 = pos + 4, p3 = pos + 6;
                int r0 = (int)lcsr[pos];
                int r1 = (p1 < le) ? (int)lcsr[p1] : SENT;
                int r2 = (p2 < le) ? (int)lcsr[p2] : SENT;
                int r3 = (p3 < le) ? (int)lcsr[p3] : SENT;
                uint4 v0 = Hp[(size_t)r0 * 8 + q];
                uint4 v1 = Hp[(size_t)r1 * 8 + q];
                uint4 v2 = Hp[(size_t)r2 * 8 + q];
                uint4 v3 = Hp[(size_t)r3 * 8 + q];
                ACC8(a, v0); ACC8(a, v1); ACC8(a, v2); ACC8(a, v3);
            }
#pragma unroll
            for (int i = 0; i < 8; ++i)
                a[i] += __shfl_xor(a[i], 8, 64);
            if (rsl == 0) {
                float rd = 1.0f / fmaxf((float)(le - lb), 1.0f);
                uint4 o;
                o.x = pack_bf16x2(a[0] * rd, a[1] * rd);
                o.y = pack_bf16x2(a[2] * rd, a[3] * rd);
                o.z = pack_bf16x2(a[4] * rd, a[5] * rd);
                o.w = pack_bf16x2(a[6] * rd, a[7] * rd);
                int s = p * 8 + q;                    // slot s <-> cols 8s..8s+7
                aggtile[nl][s ^ (nl & 7)] = o;
            }
        }
    }
    __syncthreads();

    // ---- phase B: MFMA, wave w owns cols [w*32, w*32+32) ----
    int w    = tid >> 6;                  // col-tile index 0..3
    int ml   = lane & 31;                 // local row 0..31
    int mc   = min(bk * 32 + ml, N_NODES - 1);
    int kh   = lane >> 5;

    floatx16 acc;
#pragma unroll
    for (int i = 0; i < 16; ++i) acc[i] = 0.f;

    // agg term (A from LDS, slot kh+2*ks swizzled by row)
#pragma unroll
    for (int ks = 0; ks < 8; ++ks) {
        int slot = (kh + 2 * ks) ^ (ml & 7);
        short8 aa = *(const short8*)&aggtile[ml][slot];
        int cbase = (ks * 4 + w) * 64 + lane;
        short8 bh = *(const short8*)(WfH + (size_t)cbase * 8);
        short8 bl = *(const short8*)(WfL + (size_t)cbase * 8);
        acc = __builtin_amdgcn_mfma_f32_32x32x16_bf16(aa, bh, acc, 0, 0, 0);
        acc = __builtin_amdgcn_mfma_f32_32x32x16_bf16(aa, bl, acc, 0, 0, 0);
    }
    // self term (A from 2-part-blocked global h rows)
#pragma unroll
    for (int ks = 0; ks < 8; ++ks) {
        int c8 = ks * 2 + kh;             // uint4 col-slot 0..15
        short8 aa = *(const short8*)&H4[(size_t)(c8 >> 3) * PP4 + (size_t)mc * 8 + (c8 & 7)];
        int cbase = ((8 + ks) * 4 + w) * 64 + lane;
        short8 bh = *(const short8*)(WfH + (size_t)cbase * 8);
        short8 bl = *(const short8*)(WfL + (size_t)cbase * 8);
        acc = __builtin_amdgcn_mfma_f32_32x32x16_bf16(aa, bh, acc, 0, 0, 0);
        acc = __builtin_amdgcn_mfma_f32_32x32x16_bf16(aa, bl, acc, 0, 0, 0);
    }

    int col0 = w * 32 + (lane & 31);
    float bb = b[col0];
    unsigned short* outp = outb + (size_t)(w >> 1) * (PPU * 2);   // part, ushort units
#pragma unroll
    for (int reg = 0; reg < 16; ++reg) {
        int rloc = (reg & 3) + 8 * (reg >> 2) + 4 * kh;   // C/D row map (m74/m101)
        int rowg = bk * 32 + rloc;
        if (rowg < N_NODES) {
            float v0 = acc[reg] + bb;
            if (RELU) v0 = fmaxf(v0, 0.f);
            outp[(size_t)rowg * 64 + (col0 & 63)] = f32_to_bf16(v0);
        }
    }
}

// logits from 2-part-blocked bf16 h2; 8 lanes/edge, TWO edges per lane.
// FULL-LINE loads: lane c reads uint4 slot c of part0 / part1.
__global__ void edge_dot(const int* __restrict__ esrc, const int* __restrict__ edst,
                         const unsigned* __restrict__ h2b, float* __restrict__ out) {
    int t = blockIdx.x * blockDim.x + threadIdx.x;
    int e0 = t >> 3, c = t & 7;
    const int HALF = N_LABEL / 2;
    if (e0 >= HALF) return;
    int e1 = e0 + HALF;
    const uint4* H = (const uint4*)h2b;
    int rs0 = esrc[e0], rd0 = edst[e0];
    int rs1 = esrc[e1], rd1 = edst[e1];
    uint4 a0 = H[(size_t)rs0 * 8 + c];            // src e0, part 0 (full line)
    uint4 a1 = H[PP4 + (size_t)rs0 * 8 + c];      // src e0, part 1
    uint4 b0 = H[(size_t)rd0 * 8 + c];            // dst e0, part 0
    uint4 b1 = H[PP4 + (size_t)rd0 * 8 + c];      // dst e0, part 1
    uint4 a2 = H[(size_t)rs1 * 8 + c];            // src e1, part 0
    uint4 a3 = H[PP4 + (size_t)rs1 * 8 + c];      // src e1, part 1
    uint4 b2 = H[(size_t)rd1 * 8 + c];            // dst e1, part 0
    uint4 b3 = H[PP4 + (size_t)rd1 * 8 + c];      // dst e1, part 1
    float p0 = dot8(a0, b0) + dot8(a1, b1);
    float p1 = dot8(a2, b2) + dot8(a3, b3);
#pragma unroll
    for (int off = 4; off; off >>= 1) {
        p0 += __shfl_down(p0, off, 8);
        p1 += __shfl_down(p1, off, 8);
    }
    if (c == 0) { out[e0] = p0; out[e1] = p1; }
}

extern "C" void kernel_launch(void* const* d_in, const int* in_sizes, int n_in,
                              void* d_out, int out_size, void* d_ws, size_t ws_size,
                              hipStream_t stream) {
    const int*   n_id     = (const int*)d_in[0];
    const float* x_struct = (const float*)d_in[1];
    const int*   e_idx    = (const int*)d_in[2];   // [2, N_EDGES]
    const int*   eli      = (const int*)d_in[3];   // [2, N_LABEL]
    const float* emb      = (const float*)d_in[4];
    const float* W1l      = (const float*)d_in[5];
    const float* W1r      = (const float*)d_in[6];
    const float* b1       = (const float*)d_in[7];
    const float* W2l      = (const float*)d_in[8];
    const float* W2r      = (const float*)d_in[9];
    const float* b2       = (const float*)d_in[10];
    float* out = (float*)d_out;

    const int* src = e_idx;
    const int* dst = e_idx + N_EDGES;

    const size_t ROWS = (size_t)2 * PPU;           // uints per table (2 parts)
    unsigned* hb2 = (unsigned*)d_ws;               // bf16 h2 (edge_dot input)
    unsigned* hb0 = hb2 + ROWS;                    // bf16 h0 (+sentinel)
    unsigned* hb1 = hb0 + ROWS;                    // bf16 h1 (+sentinel)
    int*   nbeg   = (int*)(hb1 + ROWS);            // relative [beg,end) per node
    int*   nend   = nbeg + N_NODES;
    int*   bcount = nend + N_NODES;                // NBUCK
    unsigned* part= (unsigned*)(bcount + NBUCK);   // NBUCK*CAP packed (src|local<<16)
    unsigned short* csr = (unsigned short*)(part + (size_t)NBUCK * CAP);  // NBUCK*CAP
    uintptr_t wa  = ((uintptr_t)(csr + (size_t)NBUCK * CAP) + 15) & ~(uintptr_t)15;
    unsigned short* WfH = (unsigned short*)wa;     // 2*32768
    unsigned short* WfL = WfH + 2 * 32768;

    // bcount <- 0 (capture-safe async memset; 6KB)
    hipMemsetAsync(bcount, 0, NBUCK * sizeof(int), stream);

    // merged front-end: LDS-hist scatter + hb0 build + W swizzle + sentinel zero
    build_all<<<NPBLK + 6283, 256, 0, stream>>>(
        n_id, emb, x_struct, hb0, hb1, src, dst, bcount, part,
        W1l, W1r, W2l, W2r, WfH, WfL);

    // layer 1: fused csr-build + aggregate + linear -> bf16 h1 (persists csr)
    fused_sage<1, 1><<<NBUCK, 256, 0, stream>>>(
        part, bcount, nbeg, nend, csr, hb0, WfH, WfL, b1, (unsigned short*)hb1);

    // layer 2: fused aggregate + linear -> bf16 h2
    fused_sage<0, 0><<<NBUCK, 256, 0, stream>>>(
        part, bcount, nbeg, nend, csr, hb1, WfH + 32768, WfL + 32768, b2,
        (unsigned short*)hb2);

    edge_dot<<<(N_LABEL / 2 * 8 + 255) / 256, 256, 0, stream>>>(
        eli, eli + N_LABEL, hb2, out);
}

// Round 16
// 203.678 us; speedup vs baseline: 1.4831x; 1.0574x over previous
//
#include <hip/hip_runtime.h>

#define N_NODES 50000
#define DIM     128
#define N_EDGES 800000
#define N_LABEL 200000
#define SENT    N_NODES      // sentinel (zero) row index, fits in ushort

// column-blocked h tables: 2 parts, part p holds cols [64p, 64p+64) of all rows.
// per part: (N_NODES+1) rows x 128B  -> gather granule = one 128B line
#define PPU ((N_NODES + 1) * 32)   // uints per part
#define PP4 ((N_NODES + 1) * 8)    // uint4 per part

// bucket partition: bucket = dst >> 5 (32 nodes/bucket), fixed capacity slots
#define NBUCK 1563           // ceil(50000/32)
#define CAP   1024           // slots per bucket (mean fill ~512, 22-sigma margin)
#define NPBLK 250            // partition blocks (measured optimum: 500 and 122us
                             // direct-atomic variants both regressed, R11/R15)
#define CHUNK 3200           // edges per partition block

typedef __attribute__((ext_vector_type(8)))  short short8;    // 8 bf16 (4 VGPRs)
typedef __attribute__((ext_vector_type(16))) float floatx16;  // 32x32 MFMA acc

// split fp32 into bf16 hi + bf16 lo (x ~= hi + lo, rel err ~2^-17), RNE both
__device__ inline void f32_to_bf16x2(float x, unsigned short& hi, unsigned short& lo) {
    unsigned u  = __float_as_uint(x);
    unsigned rh = (u + 0x7FFFu + ((u >> 16) & 1u)) >> 16;
    hi = (unsigned short)rh;
    float hif = __uint_as_float(rh << 16);
    float r = x - hif;
    unsigned ul = __float_as_uint(r);
    unsigned rl = (ul + 0x7FFFu + ((ul >> 16) & 1u)) >> 16;
    lo = (unsigned short)rl;
}

__device__ inline unsigned short f32_to_bf16(float x) {
    unsigned u = __float_as_uint(x);
    return (unsigned short)((u + 0x7FFFu + ((u >> 16) & 1u)) >> 16);
}

__device__ inline unsigned pack_bf16x2(float a, float b) {
    return (unsigned)f32_to_bf16(a) | ((unsigned)f32_to_bf16(b) << 16);
}

__device__ inline float bf_lo(unsigned u) { return __uint_as_float(u << 16); }
__device__ inline float bf_hi(unsigned u) { return __uint_as_float(u & 0xFFFF0000u); }

__device__ inline float dot8(uint4 a, uint4 b) {
    return bf_lo(a.x) * bf_lo(b.x) + bf_hi(a.x) * bf_hi(b.x)
         + bf_lo(a.y) * bf_lo(b.y) + bf_hi(a.y) * bf_hi(b.y)
         + bf_lo(a.z) * bf_lo(b.z) + bf_hi(a.z) * bf_hi(b.z)
         + bf_lo(a.w) * bf_lo(b.w) + bf_hi(a.w) * bf_hi(b.w);
}

// MERGED front-end (bcount pre-zeroed by hipMemsetAsync):
//  [0, NPBLK): graph-edge part_scatter chunks (LDS hist + range-reserve: ~1
//    global atomic per (block,bucket) -> low contention. NEVER direct-atomic:
//    R11 measured 122us from 512-deep same-address atomic serialization.)
//  [NPBLK, NPBLK+6250): build hb0 (2-part-blocked bf16)
//  [.., +6282): swizzle W
//  last: zero sentinel rows of hb0/hb1
__global__ __launch_bounds__(256)
void build_all(const int* __restrict__ n_id,
               const float* __restrict__ emb,
               const float* __restrict__ xs,
               unsigned* __restrict__ hb0, unsigned* __restrict__ hb1,
               const int* __restrict__ src, const int* __restrict__ dst,
               int* __restrict__ bcount, unsigned* __restrict__ part,
               const float* __restrict__ W1l, const float* __restrict__ W1r,
               const float* __restrict__ W2l, const float* __restrict__ W2r,
               unsigned short* __restrict__ WfH, unsigned short* __restrict__ WfL) {
    if (blockIdx.x < NPBLK) {
        // fused hist + range-reserve + grouped scatter for one graph-edge chunk
        __shared__ int hist[NBUCK];      // pass1: counts; pass2: write cursors
        int t = threadIdx.x;
        for (int i = t; i < NBUCK; i += 256) hist[i] = 0;
        __syncthreads();
        int base = blockIdx.x * CHUNK;
        for (int e = base + t; e < base + CHUNK; e += 256)
            atomicAdd(&hist[dst[e] >> 5], 1);
        __syncthreads();
        for (int i = t; i < NBUCK; i += 256) {
            int c = hist[i];
            hist[i] = c ? atomicAdd(&bcount[i], c) : 0;   // reserve [base, base+c)
        }
        __syncthreads();
        for (int e = base + t; e < base + CHUNK; e += 256) {
            int d = dst[e];
            int bk = d >> 5;
            int pos = atomicAdd(&hist[bk], 1);
            part[bk * CAP + pos] = (unsigned)src[e] | ((unsigned)(d & 31) << 16);
        }
    } else if (blockIdx.x < NPBLK + 6250) {
        int t = (blockIdx.x - NPBLK) * 256 + threadIdx.x;   // < N_NODES*32 exactly
        int i = t >> 5, c = t & 31;                 // c covers cols 4c..4c+3
        float4 v;
        if (c < 16) {
            int nid = n_id[i];
            v = ((const float4*)emb)[nid * 16 + c];
        } else {
            v = ((const float4*)xs)[i * 16 + (c - 16)];
        }
        uint2 p;
        p.x = pack_bf16x2(v.x, v.y);
        p.y = pack_bf16x2(v.z, v.w);
        int pt = c >> 4;                            // part 0..1 (16 uint2 per part-row)
        ((uint2*)hb0)[(size_t)pt * (PPU / 2) + (size_t)i * 16 + (c & 15)] = p;
    } else if (blockIdx.x < NPBLK + 6282) {
        int t = (blockIdx.x - NPBLK - 6250) * 256 + threadIdx.x;   // 8192 chunks
        if (t >= 8192) return;
        int L  = t & 63;
        int nt = (t >> 6) & 3;
        int ks = (t >> 8) & 7;
        int p  = (t >> 11) & 1;
        int ly = t >> 12;
        const float* Ws[4] = {W1l, W1r, W2l, W2r};
        const float* W = Ws[ly * 2 + p];
        int n = nt * 32 + (L & 31);
        int kbase = ks * 16 + (L >> 5) * 8;
        short8 hv, lv;
#pragma unroll
        for (int j = 0; j < 8; ++j) {
            unsigned short hh, ll;
            f32_to_bf16x2(W[(kbase + j) * DIM + n], hh, ll);
            hv[j] = (short)hh;
            lv[j] = (short)ll;
        }
        *(short8*)(WfH + (size_t)t * 8) = hv;
        *(short8*)(WfL + (size_t)t * 8) = lv;
    } else {
        // zero sentinel rows (row SENT) of both parts of hb0 and hb1
        int u = threadIdx.x;
        if (u < 64) {
            int p = u >> 5;
            hb0[(size_t)p * PPU + (size_t)SENT * 32 + (u & 31)] = 0;
        } else if (u < 128) {
            int v = u - 64;
            int p = v >> 5;
            hb1[(size_t)p * PPU + (size_t)SENT * 32 + (v & 31)] = 0;
        }
    }
}

#define ACC8(A, v) { A[0]+=bf_lo((v).x); A[1]+=bf_hi((v).x); A[2]+=bf_lo((v).y); A[3]+=bf_hi((v).y); \
                     A[4]+=bf_lo((v).z); A[5]+=bf_hi((v).z); A[6]+=bf_lo((v).w); A[7]+=bf_hi((v).w); }

// FUSED csr-build + aggregate + linear, one 32-node tile (== csr bucket).
// CSRB=1 (layer 1): prologue builds localized csr in LDS from part[] and persists
//   lcsr + relative nbeg/nend for layer 2. CSRB=0 (layer 2): stages persisted csr.
// Gather (128B granule): 2 column phases over 2-part-blocked h; per 16-lane group:
//   q=c&7 (uint4 slot of the 128B row-slice), rsl=c>>3 (2 interleaved position
//   chains); 4 rows x 128B in flight per burst; shfl_xor(8) reduce.
// Phase B: 4 waves, wave w owns cols [32w, 32w+32).
template <int RELU, int CSRB>
__global__ __launch_bounds__(256, 7)
void fused_sage(const unsigned* __restrict__ part, const int* __restrict__ bcount,
                int* __restrict__ nbeg, int* __restrict__ nend,
                unsigned short* __restrict__ csr,
                const unsigned* __restrict__ hsrc,
                const unsigned short* __restrict__ WfH,
                const unsigned short* __restrict__ WfL,
                const float* __restrict__ b,
                unsigned short* __restrict__ outb) {
    __shared__ uint4 aggtile[32][16];        // 8KB bf16 agg tile, swizzled slots
    __shared__ unsigned short lcsr[CAP];     // 2KB staged/built csr bucket
    __shared__ int lbe[32][2];               // per-node [beg,end) relative
    __shared__ int ldeg[32];
    __shared__ int lcur[32];
    int tid  = threadIdx.x;
    int lane = tid & 63;
    int g    = tid >> 4;                  // 16-lane group id (0..15)
    int c    = tid & 15;
    int bk   = blockIdx.x;
    int base = bk * CAP;
    int cnt  = bcount[bk];

    if (CSRB) {
        // ---- bucket_csr fused in: hist -> scan -> scatter (LDS-local) ----
        if (tid < 32) ldeg[tid] = 0;
        __syncthreads();
        for (int e = tid; e < cnt; e += 256)
            atomicAdd(&ldeg[part[base + e] >> 16], 1);
        __syncthreads();
        if (tid < 32) {                   // 32-wide scan in wave 0
            int v = ldeg[tid];
            int s = v;
#pragma unroll
            for (int off = 1; off < 32; off <<= 1) {
                int u = __shfl_up(s, off, 32);
                if (tid >= off) s += u;
            }
            int excl = s - v;
            lbe[tid][0] = excl;
            lbe[tid][1] = excl + v;
            lcur[tid]   = excl;
            int node = bk * 32 + tid;
            if (node < N_NODES) { nbeg[node] = excl; nend[node] = excl + v; }
        }
        __syncthreads();
        for (int e = tid; e < cnt; e += 256) {
            unsigned p = part[base + e];
            int pos = atomicAdd(&lcur[p >> 16], 1);
            lcsr[pos] = (unsigned short)(p & 0xFFFFu);
        }
        __syncthreads();
        // persist localized csr for layer 2 (fire-and-forget stores)
        for (int e = tid; e < cnt; e += 256) csr[base + e] = lcsr[e];
    } else {
        for (int e = tid; e < cnt; e += 256) lcsr[e] = csr[base + e];
        if (tid < 32) {
            int node = bk * 32 + tid;
            int b0 = 0, e0 = 0;
            if (node < N_NODES) { b0 = nbeg[node]; e0 = nend[node]; }
            lbe[tid][0] = b0; lbe[tid][1] = e0;
        }
        __syncthreads();
    }

    const uint4* H4 = (const uint4*)hsrc;
    int q   = c & 7;                      // uint4 col-slot within 128B row-slice
    int rsl = c >> 3;                     // position chain 0..1

    // ---- phase A: 2 column phases (no inter-phase sync; slots disjoint) ----
    for (int p = 0; p < 2; ++p) {
        const uint4* Hp = H4 + (size_t)p * PP4;
#pragma unroll
        for (int nn = 0; nn < 2; ++nn) {
            int nl = g + nn * 16;
            int lb = lbe[nl][0], le = lbe[nl][1];
            float a[8] = {0.f,0.f,0.f,0.f,0.f,0.f,0.f,0.f};
            for (int pos = lb + rsl; pos < le; pos += 8) {
                int p1 = pos + 2, p2 = pos + 4, p3 = pos + 6;
                int r0 = (int)lcsr[pos];
                int r1 = (p1 < le) ? (int)lcsr[p1] : SENT;
                int r2 = (p2 < le) ? (int)lcsr[p2] : SENT;
                int r3 = (p3 < le) ? (int)lcsr[p3] : SENT;
                uint4 v0 = Hp[(size_t)r0 * 8 + q];
                uint4 v1 = Hp[(size_t)r1 * 8 + q];
                uint4 v2 = Hp[(size_t)r2 * 8 + q];
                uint4 v3 = Hp[(size_t)r3 * 8 + q];
                ACC8(a, v0); ACC8(a, v1); ACC8(a, v2); ACC8(a, v3);
            }
#pragma unroll
            for (int i = 0; i < 8; ++i)
                a[i] += __shfl_xor(a[i], 8, 64);
            if (rsl == 0) {
                float rd = 1.0f / fmaxf((float)(le - lb), 1.0f);
                uint4 o;
                o.x = pack_bf16x2(a[0] * rd, a[1] * rd);
                o.y = pack_bf16x2(a[2] * rd, a[3] * rd);
                o.z = pack_bf16x2(a[4] * rd, a[5] * rd);
                o.w = pack_bf16x2(a[6] * rd, a[7] * rd);
                int s = p * 8 + q;                    // slot s <-> cols 8s..8s+7
                aggtile[nl][s ^ (nl & 7)] = o;
            }
        }
    }
    __syncthreads();

    // ---- phase B: MFMA, wave w owns cols [w*32, w*32+32) ----
    int w    = tid >> 6;                  // col-tile index 0..3
    int ml   = lane & 31;                 // local row 0..31
    int mc   = min(bk * 32 + ml, N_NODES - 1);
    int kh   = lane >> 5;

    floatx16 acc;
#pragma unroll
    for (int i = 0; i < 16; ++i) acc[i] = 0.f;

    // agg term (A from LDS, slot kh+2*ks swizzled by row)
#pragma unroll
    for (int ks = 0; ks < 8; ++ks) {
        int slot = (kh + 2 * ks) ^ (ml & 7);
        short8 aa = *(const short8*)&aggtile[ml][slot];
        int cbase = (ks * 4 + w) * 64 + lane;
        short8 bh = *(const short8*)(WfH + (size_t)cbase * 8);
        short8 bl = *(const short8*)(WfL + (size_t)cbase * 8);
        acc = __builtin_amdgcn_mfma_f32_32x32x16_bf16(aa, bh, acc, 0, 0, 0);
        acc = __builtin_amdgcn_mfma_f32_32x32x16_bf16(aa, bl, acc, 0, 0, 0);
    }
    // self term (A from 2-part-blocked global h rows)
#pragma unroll
    for (int ks = 0; ks < 8; ++ks) {
        int c8 = ks * 2 + kh;             // uint4 col-slot 0..15
        short8 aa = *(const short8*)&H4[(size_t)(c8 >> 3) * PP4 + (size_t)mc * 8 + (c8 & 7)];
        int cbase = ((8 + ks) * 4 + w) * 64 + lane;
        short8 bh = *(const short8*)(WfH + (size_t)cbase * 8);
        short8 bl = *(const short8*)(WfL + (size_t)cbase * 8);
        acc = __builtin_amdgcn_mfma_f32_32x32x16_bf16(aa, bh, acc, 0, 0, 0);
        acc = __builtin_amdgcn_mfma_f32_32x32x16_bf16(aa, bl, acc, 0, 0, 0);
    }

    int col0 = w * 32 + (lane & 31);
    float bb = b[col0];
    unsigned short* outp = outb + (size_t)(w >> 1) * (PPU * 2);   // part, ushort units
#pragma unroll
    for (int reg = 0; reg < 16; ++reg) {
        int rloc = (reg & 3) + 8 * (reg >> 2) + 4 * kh;   // C/D row map (m74/m101)
        int rowg = bk * 32 + rloc;
        if (rowg < N_NODES) {
            float v0 = acc[reg] + bb;
            if (RELU) v0 = fmaxf(v0, 0.f);
            outp[(size_t)rowg * 64 + (col0 & 63)] = f32_to_bf16(v0);
        }
    }
}

// logits from 2-part-blocked bf16 h2; 8 lanes/edge, TWO edges per lane.
// FULL-LINE loads: lane c reads uint4 slot c of part0 / part1.
__global__ void edge_dot(const int* __restrict__ esrc, const int* __restrict__ edst,
                         const unsigned* __restrict__ h2b, float* __restrict__ out) {
    int t = blockIdx.x * blockDim.x + threadIdx.x;
    int e0 = t >> 3, c = t & 7;
    const int HALF = N_LABEL / 2;
    if (e0 >= HALF) return;
    int e1 = e0 + HALF;
    const uint4* H = (const uint4*)h2b;
    int rs0 = esrc[e0], rd0 = edst[e0];
    int rs1 = esrc[e1], rd1 = edst[e1];
    uint4 a0 = H[(size_t)rs0 * 8 + c];            // src e0, part 0 (full line)
    uint4 a1 = H[PP4 + (size_t)rs0 * 8 + c];      // src e0, part 1
    uint4 b0 = H[(size_t)rd0 * 8 + c];            // dst e0, part 0
    uint4 b1 = H[PP4 + (size_t)rd0 * 8 + c];      // dst e0, part 1
    uint4 a2 = H[(size_t)rs1 * 8 + c];            // src e1, part 0
    uint4 a3 = H[PP4 + (size_t)rs1 * 8 + c];      // src e1, part 1
    uint4 b2 = H[(size_t)rd1 * 8 + c];            // dst e1, part 0
    uint4 b3 = H[PP4 + (size_t)rd1 * 8 + c];      // dst e1, part 1
    float p0 = dot8(a0, b0) + dot8(a1, b1);
    float p1 = dot8(a2, b2) + dot8(a3, b3);
#pragma unroll
    for (int off = 4; off; off >>= 1) {
        p0 += __shfl_down(p0, off, 8);
        p1 += __shfl_down(p1, off, 8);
    }
    if (c == 0) { out[e0] = p0; out[e1] = p1; }
}

extern "C" void kernel_launch(void* const* d_in, const int* in_sizes, int n_in,
                              void* d_out, int out_size, void* d_ws, size_t ws_size,
                              hipStream_t stream) {
    const int*   n_id     = (const int*)d_in[0];
    const float* x_struct = (const float*)d_in[1];
    const int*   e_idx    = (const int*)d_in[2];   // [2, N_EDGES]
    const int*   eli      = (const int*)d_in[3];   // [2, N_LABEL]
    const float* emb      = (const float*)d_in[4];
    const float* W1l      = (const float*)d_in[5];
    const float* W1r      = (const float*)d_in[6];
    const float* b1       = (const float*)d_in[7];
    const float* W2l      = (const float*)d_in[8];
    const float* W2r      = (const float*)d_in[9];
    const float* b2       = (const float*)d_in[10];
    float* out = (float*)d_out;

    const int* src = e_idx;
    const int* dst = e_idx + N_EDGES;

    const size_t ROWS = (size_t)2 * PPU;           // uints per table (2 parts)
    unsigned* hb2 = (unsigned*)d_ws;               // bf16 h2 (edge_dot input)
    unsigned* hb0 = hb2 + ROWS;                    // bf16 h0 (+sentinel)
    unsigned* hb1 = hb0 + ROWS;                    // bf16 h1 (+sentinel)
    int*   nbeg   = (int*)(hb1 + ROWS);            // relative [beg,end) per node
    int*   nend   = nbeg + N_NODES;
    int*   bcount = nend + N_NODES;                // NBUCK
    unsigned* part= (unsigned*)(bcount + NBUCK);   // NBUCK*CAP packed (src|local<<16)
    unsigned short* csr = (unsigned short*)(part + (size_t)NBUCK * CAP);  // NBUCK*CAP
    uintptr_t wa  = ((uintptr_t)(csr + (size_t)NBUCK * CAP) + 15) & ~(uintptr_t)15;
    unsigned short* WfH = (unsigned short*)wa;     // 2*32768
    unsigned short* WfL = WfH + 2 * 32768;

    // bcount <- 0 (capture-safe async memset; 6KB)
    hipMemsetAsync(bcount, 0, NBUCK * sizeof(int), stream);

    // merged front-end: LDS-hist scatter + hb0 build + W swizzle + sentinel zero
    build_all<<<NPBLK + 6283, 256, 0, stream>>>(
        n_id, emb, x_struct, hb0, hb1, src, dst, bcount, part,
        W1l, W1r, W2l, W2r, WfH, WfL);

    // layer 1: fused csr-build + aggregate + linear -> bf16 h1 (persists csr)
    fused_sage<1, 1><<<NBUCK, 256, 0, stream>>>(
        part, bcount, nbeg, nend, csr, hb0, WfH, WfL, b1, (unsigned short*)hb1);

    // layer 2: fused aggregate + linear -> bf16 h2
    fused_sage<0, 0><<<NBUCK, 256, 0, stream>>>(
        part, bcount, nbeg, nend, csr, hb1, WfH + 32768, WfL + 32768, b2,
        (unsigned short*)hb2);

    edge_dot<<<(N_LABEL / 2 * 8 + 255) / 256, 256, 0, stream>>>(
        eli, eli + N_LABEL, hb2, out);
}